// Round 21
// baseline (167.810 us; speedup 1.0000x reference)
//
#include <hip/hip_runtime.h>
#include <hip/hip_bf16.h>
#include <hip/hip_fp16.h>

// GCN 3-layer embedder. Single-pass dual counting-sort into FIXED-CAPACITY
// coarse buckets (node>>6, CAP=1280; mean 1024, +8 sigma).
// GEMM epilogue scales rows by dinv: u = dinv.*(A@W) stored fp16, so
//   Agg(t)[i] = dinv_i * ( sum_{e: dst=i} u[src_e] + u[i] )
// Layer 3 + mean collapsed:
//   out = ((sum_i w_i * h2[i]) @ W3)/N + b3,  w_i = dinv_i^2 + dinv_i * srcw_i
// wreduce: 1 block per src-bucket, inline srcw, vectorized (R19: 45->~5us).
// scatter: EPB 2048 (392 blocks) -- R16 showed 20% occupancy at 196 blocks.
// agg: 2 nodes/wave, batch-8 row-gathers in flight (random-HBM-read bound).
// NT stores measured -54 us (scattered NT writes lose L2 write-combining): don't.
// srcw/dinv cross-node deps only safe across kernel boundaries (R17 raced).

#define C 128
#define EPB 2048        // edges per block in the scatter kernel (1024 thr x 2)
#define NBINS 1024      // coarse bins (node>>6); 782 used
#define LOWM 63
#define CAP 1280        // bucket capacity (mean 1024, sigma 32)

typedef __attribute__((ext_vector_type(8))) _Float16 half8;
typedef __attribute__((ext_vector_type(4))) float float4v;

__device__ inline void addrow(float4& a0, float4& a1, uint4 uv) {
    float2 f0 = __half22float2(*(__half2*)&uv.x);
    float2 f1 = __half22float2(*(__half2*)&uv.y);
    float2 f2 = __half22float2(*(__half2*)&uv.z);
    float2 f3 = __half22float2(*(__half2*)&uv.w);
    a0.x += f0.x; a0.y += f0.y; a0.z += f1.x; a0.w += f1.y;
    a1.x += f2.x; a1.y += f2.y; a1.z += f3.x; a1.w += f3.y;
}

// ---------------- B1: single-pass dual scatter into fixed-cap buckets ----------------
__global__ __launch_bounds__(1024) void coarse_scatter(const int* __restrict__ ei, int E,
                                                       int* __restrict__ ccntD,
                                                       int* __restrict__ ccntS,
                                                       unsigned int* __restrict__ interD,
                                                       unsigned int* __restrict__ interS) {
    __shared__ int histD[2][NBINS];
    __shared__ int histS[2][NBINS];
    __shared__ int baseD[NBINS], curD[NBINS], baseS[NBINS], curS[NBINS];
    const int t = threadIdx.x, grp = t >> 9;
    histD[0][t] = 0; histD[1][t] = 0; histS[0][t] = 0; histS[1][t] = 0;
    curD[t] = 0; curS[t] = 0;
    __syncthreads();
    int blk = blockIdx.x * EPB;
    int dst[2], src[2];
#pragma unroll
    for (int i = 0; i < 2; ++i) {
        int e = blk + t + i * 1024;
        dst[i] = -1;
        if (e < E) {
            dst[i] = ei[E + e];
            src[i] = ei[e];
            atomicAdd(&histD[grp][dst[i] >> 6], 1);
            atomicAdd(&histS[grp][src[i] >> 6], 1);
        }
    }
    __syncthreads();
    {
        int hD = histD[0][t] + histD[1][t];
        if (hD) baseD[t] = t * CAP + atomicAdd(&ccntD[t], hD);
        int hS = histS[0][t] + histS[1][t];
        if (hS) baseS[t] = t * CAP + atomicAdd(&ccntS[t], hS);
    }
    __syncthreads();
#pragma unroll
    for (int i = 0; i < 2; ++i) {
        if (dst[i] >= 0) {
            int binD = dst[i] >> 6;
            int rD = atomicAdd(&curD[binD], 1);
            interD[baseD[binD] + rD] = ((unsigned int)src[i] << 6) | (unsigned int)(dst[i] & LOWM);
            int binS = src[i] >> 6;
            int rS = atomicAdd(&curS[binS], 1);
            interS[baseS[binS] + rS] = ((unsigned int)dst[i] << 6) | (unsigned int)(src[i] & LOWM);
        }
    }
}

// ---------------- B2: per-dst-bucket finalize: rowbeg, rowcnt, dinv, csr ----------------
__global__ __launch_bounds__(256) void bucket_build(const unsigned int* __restrict__ inter,
                                                    const int* __restrict__ ccntD,
                                                    int N, ushort* __restrict__ csr,
                                                    int* __restrict__ rowbeg,
                                                    int* __restrict__ rowcnt,
                                                    float* __restrict__ dinv) {
    __shared__ int hist[4][64];
    __shared__ int excl[64], cur[64], sc[64];
    const int b = blockIdx.x, t = threadIdx.x, grp = t >> 6;
    const int lo = b * CAP, n = ccntD[b];

    if (t < 64) { hist[0][t] = 0; hist[1][t] = 0; hist[2][t] = 0; hist[3][t] = 0; cur[t] = 0; }
    __syncthreads();
    for (int i = t; i < n; i += 256) atomicAdd(&hist[grp][inter[lo + i] & LOWM], 1);
    __syncthreads();
    int v = 0;
    if (t < 64) { v = hist[0][t] + hist[1][t] + hist[2][t] + hist[3][t]; sc[t] = v; }
    __syncthreads();
    for (int o = 1; o < 64; o <<= 1) {
        int x = 0;
        if (t < 64 && t >= o) x = sc[t - o];
        __syncthreads();
        if (t < 64) sc[t] += x;
        __syncthreads();
    }
    if (t < 64) {
        int ex = sc[t] - v;
        excl[t] = ex;
        int node = b * 64 + t;
        if (node < N) {
            rowbeg[node] = lo + ex;
            rowcnt[node] = v;
            dinv[node] = rsqrtf((float)v + 1.0f);
        }
    }
    __syncthreads();
    for (int i = t; i < n; i += 256) {
        unsigned int pv = inter[lo + i];
        int r = atomicAdd(&cur[pv & LOWM], 1);
        csr[lo + excl[pv & LOWM] + r] = (ushort)(pv >> 6);
    }
}

// ---------------- weight prep: Wt[c][k] = (fp16) W[k][c], for W1,W2 ----------------
__global__ __launch_bounds__(128) void wprep(const float* __restrict__ W1,
                                             const float* __restrict__ W2,
                                             __half* __restrict__ Wt1,
                                             __half* __restrict__ Wt2) {
    const float* W = blockIdx.y ? W2 : W1;
    __half* Wt = blockIdx.y ? Wt2 : Wt1;
    int c = blockIdx.x, k = threadIdx.x;
    Wt[c * 128 + k] = __float2half(W[k * 128 + c]);
}

// ---------------- MFMA GEMM: U[M x 128] = dinv .* (A[M x 128] @ W), fp16 out ----------------
template<bool AF32>
__global__ __launch_bounds__(256) void gemm_mfma(const void* __restrict__ Aptr,
                                                 const __half* __restrict__ Wt,
                                                 const float* __restrict__ dinv,
                                                 ushort* __restrict__ U, int M) {
    __shared__ _Float16 Wsh[128 * 128];   // 32 KB, XOR-swizzled
    const int t = threadIdx.x;

    const float4* Wg4 = (const float4*)Wt;
    float4* Ws4 = (float4*)Wsh;
#pragma unroll
    for (int i = 0; i < 8; ++i) {
        int idx = t + i * 256;
        int row = idx >> 4;
        Ws4[(idx & ~15) | ((idx ^ row) & 7) | (idx & 8)] = Wg4[idx];
    }

    const int wave = t >> 6, lane = t & 63;
    const int row0 = blockIdx.x * 64 + wave * 16;
    const int lr = lane & 15;
    const int lk = lane >> 4;

    half8 afrag[4];
    {
        int gr = row0 + lr; if (gr >= M) gr = M - 1;
        if (AF32) {
            const float* A = (const float*)Aptr;
            const float* ap = A + (size_t)gr * 128 + lk * 8;
#pragma unroll
            for (int ks = 0; ks < 4; ++ks) {
                float4 v0 = *(const float4*)(ap + ks * 32);
                float4 v1 = *(const float4*)(ap + ks * 32 + 4);
                half8 a;
                a[0] = (_Float16)v0.x; a[1] = (_Float16)v0.y; a[2] = (_Float16)v0.z; a[3] = (_Float16)v0.w;
                a[4] = (_Float16)v1.x; a[5] = (_Float16)v1.y; a[6] = (_Float16)v1.z; a[7] = (_Float16)v1.w;
                afrag[ks] = a;
            }
        } else {
            const _Float16* A = (const _Float16*)Aptr;
            const _Float16* ap = A + (size_t)gr * 128 + lk * 8;
#pragma unroll
            for (int ks = 0; ks < 4; ++ks) afrag[ks] = *(const half8*)(ap + ks * 32);
        }
    }

    __syncthreads();

    float4v acc[8];
#pragma unroll
    for (int n = 0; n < 8; ++n) acc[n] = (float4v)0.f;

#pragma unroll
    for (int n = 0; n < 8; ++n) {
        int brow = n * 16 + lr;
#pragma unroll
        for (int ks = 0; ks < 4; ++ks) {
            int f4 = ks * 4 + lk;
            int swz = (f4 & 8) | ((f4 ^ brow) & 7);
            half8 bfr = *(const half8*)(Wsh + (size_t)brow * 128 + swz * 8);
            acc[n] = __builtin_amdgcn_mfma_f32_16x16x32_f16(afrag[ks], bfr, acc[n], 0, 0, 0);
        }
    }

    float dv[4];
#pragma unroll
    for (int r = 0; r < 4; ++r) {
        int gr = row0 + lk * 4 + r;
        dv[r] = (gr < M) ? dinv[gr] : 0.f;
    }
#pragma unroll
    for (int n = 0; n < 8; ++n) {
#pragma unroll
        for (int r = 0; r < 4; ++r) {
            int gr = row0 + lk * 4 + r;
            if (gr < M) {
                __half hv = __float2half(acc[n][r] * dv[r]);
                U[(size_t)gr * 128 + n * 16 + lr] = *(const ushort*)&hv;
            }
        }
    }
}

// ---------------- CSR aggregate: 2 nodes/wave, 8 batched gathers in flight ----------------
__global__ __launch_bounds__(256) void agg_kernel(const int* __restrict__ rowbeg,
                                                  const int* __restrict__ rowcnt,
                                                  const ushort* __restrict__ csr,
                                                  const uint4* __restrict__ u,   // row = 16 uint4
                                                  const float* __restrict__ dinv,
                                                  const float* __restrict__ b,
                                                  uint4* __restrict__ h, int N) {
    int wid = (blockIdx.x * 256 + threadIdx.x) >> 6;
    int n0 = wid * 2;
    if (n0 >= N) return;
    int n1 = n0 + 1;
    bool has1 = n1 < N;
    int lane = threadIdx.x & 63;
    int c8 = lane & 15;          // uint4 index within row
    int g = lane >> 4;           // group 0..3

    int beg0 = rowbeg[n0], end0 = beg0 + rowcnt[n0];
    int beg1 = has1 ? rowbeg[n1] : 0;
    int end1 = has1 ? beg1 + rowcnt[n1] : 0;

    float4 A0 = make_float4(0.f,0.f,0.f,0.f), A1 = A0, B0 = A0, B1 = A0;
    if (g == 0) {                // self-loop terms
        addrow(A0, A1, u[(size_t)n0 * 16 + c8]);
        if (has1) addrow(B0, B1, u[(size_t)n1 * 16 + c8]);
    }

    int k0 = beg0, k1 = beg1;
    while (k0 < end0 || k1 < end1) {
        int cn0 = end0 - k0; cn0 = cn0 < 0 ? 0 : (cn0 > 16 ? 16 : cn0);
        int cn1 = end1 - k1; cn1 = cn1 < 0 ? 0 : (cn1 > 16 ? 16 : cn1);
        int s0 = (lane < cn0) ? (int)csr[k0 + lane] : 0;
        int s1 = (lane < cn1) ? (int)csr[k1 + lane] : 0;
        uint4 r0[4], r1[4];
#pragma unroll
        for (int j = 0; j < 4; ++j) {                      // issue all 8 loads first
            int sj0 = __shfl(s0, g + j * 4);
            int sj1 = __shfl(s1, g + j * 4);
            r0[j] = u[(size_t)sj0 * 16 + c8];
            r1[j] = u[(size_t)sj1 * 16 + c8];
        }
#pragma unroll
        for (int j = 0; j < 4; ++j) {                      // then consume
            int e = g + j * 4;
            if (e < cn0) addrow(A0, A1, r0[j]);
            if (e < cn1) addrow(B0, B1, r1[j]);
        }
        k0 += 16; k1 += 16;
    }

    // combine 4 groups
#pragma unroll
    for (int m = 16; m <= 32; m <<= 1) {
        A0.x += __shfl_xor(A0.x, m); A0.y += __shfl_xor(A0.y, m);
        A0.z += __shfl_xor(A0.z, m); A0.w += __shfl_xor(A0.w, m);
        A1.x += __shfl_xor(A1.x, m); A1.y += __shfl_xor(A1.y, m);
        A1.z += __shfl_xor(A1.z, m); A1.w += __shfl_xor(A1.w, m);
        B0.x += __shfl_xor(B0.x, m); B0.y += __shfl_xor(B0.y, m);
        B0.z += __shfl_xor(B0.z, m); B0.w += __shfl_xor(B0.w, m);
        B1.x += __shfl_xor(B1.x, m); B1.y += __shfl_xor(B1.y, m);
        B1.z += __shfl_xor(B1.z, m); B1.w += __shfl_xor(B1.w, m);
    }

    if (g == 0) {
        float4 bv0 = ((const float4*)b)[c8 * 2];
        float4 bv1 = ((const float4*)b)[c8 * 2 + 1];
        {
            float di = dinv[n0];
            float4 r0v, r1v;
            r0v.x = fmaxf(fmaf(A0.x, di, bv0.x), 0.f);
            r0v.y = fmaxf(fmaf(A0.y, di, bv0.y), 0.f);
            r0v.z = fmaxf(fmaf(A0.z, di, bv0.z), 0.f);
            r0v.w = fmaxf(fmaf(A0.w, di, bv0.w), 0.f);
            r1v.x = fmaxf(fmaf(A1.x, di, bv1.x), 0.f);
            r1v.y = fmaxf(fmaf(A1.y, di, bv1.y), 0.f);
            r1v.z = fmaxf(fmaf(A1.z, di, bv1.z), 0.f);
            r1v.w = fmaxf(fmaf(A1.w, di, bv1.w), 0.f);
            __half2 p0 = __floats2half2_rn(r0v.x, r0v.y);
            __half2 p1 = __floats2half2_rn(r0v.z, r0v.w);
            __half2 p2 = __floats2half2_rn(r1v.x, r1v.y);
            __half2 p3 = __floats2half2_rn(r1v.z, r1v.w);
            uint4 o;
            o.x = *(const unsigned int*)&p0;
            o.y = *(const unsigned int*)&p1;
            o.z = *(const unsigned int*)&p2;
            o.w = *(const unsigned int*)&p3;
            h[(size_t)n0 * 16 + c8] = o;
        }
        if (has1) {
            float di = dinv[n1];
            float4 r0v, r1v;
            r0v.x = fmaxf(fmaf(B0.x, di, bv0.x), 0.f);
            r0v.y = fmaxf(fmaf(B0.y, di, bv0.y), 0.f);
            r0v.z = fmaxf(fmaf(B0.z, di, bv0.z), 0.f);
            r0v.w = fmaxf(fmaf(B0.w, di, bv0.w), 0.f);
            r1v.x = fmaxf(fmaf(B1.x, di, bv1.x), 0.f);
            r1v.y = fmaxf(fmaf(B1.y, di, bv1.y), 0.f);
            r1v.z = fmaxf(fmaf(B1.z, di, bv1.z), 0.f);
            r1v.w = fmaxf(fmaf(B1.w, di, bv1.w), 0.f);
            __half2 p0 = __floats2half2_rn(r0v.x, r0v.y);
            __half2 p1 = __floats2half2_rn(r0v.z, r0v.w);
            __half2 p2 = __floats2half2_rn(r1v.x, r1v.y);
            __half2 p3 = __floats2half2_rn(r1v.z, r1v.w);
            uint4 o;
            o.x = *(const unsigned int*)&p0;
            o.y = *(const unsigned int*)&p1;
            o.z = *(const unsigned int*)&p2;
            o.w = *(const unsigned int*)&p3;
            h[(size_t)n1 * 16 + c8] = o;
        }
    }
}

// ---------------- wreduce: 1 block per src-bucket (64 nodes), vectorized ----------------
__global__ __launch_bounds__(256) void wreduce(const __half* __restrict__ h,
                                               const float* __restrict__ dinv,
                                               const unsigned int* __restrict__ interS,
                                               const int* __restrict__ ccntS,
                                               float* __restrict__ v, int N) {
    __shared__ float facc[64];
    __shared__ float wsh[64];
    __shared__ float red[4][16][8];
    const int b = blockIdx.x, t = threadIdx.x;
    if (t < 64) facc[t] = 0.f;
    __syncthreads();
    {
        int lo = b * CAP, hi = lo + ccntS[b];
        for (int i = lo + t; i < hi; i += 256) {
            unsigned int pv = interS[i];
            atomicAdd(&facc[pv & LOWM], dinv[pv >> 6]);
        }
    }
    __syncthreads();
    if (t < 64) {
        int node = b * 64 + t;
        float w = 0.f;
        if (node < N) { float di = dinv[node]; w = di * (di + facc[t]); }
        wsh[t] = w;
    }
    __syncthreads();

    const int nl = t >> 4;       // node lane 0..15
    const int c8 = t & 15;       // uint4 column
    const uint4* h4 = (const uint4*)h;
    float acc[8];
#pragma unroll
    for (int j = 0; j < 8; ++j) acc[j] = 0.f;
#pragma unroll
    for (int i = 0; i < 4; ++i) {
        int idx = nl + i * 16;
        int node = b * 64 + idx;
        if (node < N) {
            float w = wsh[idx];
            uint4 uv = h4[(size_t)node * 16 + c8];
            float2 f0 = __half22float2(*(__half2*)&uv.x);
            float2 f1 = __half22float2(*(__half2*)&uv.y);
            float2 f2 = __half22float2(*(__half2*)&uv.z);
            float2 f3 = __half22float2(*(__half2*)&uv.w);
            acc[0] = fmaf(f0.x, w, acc[0]); acc[1] = fmaf(f0.y, w, acc[1]);
            acc[2] = fmaf(f1.x, w, acc[2]); acc[3] = fmaf(f1.y, w, acc[3]);
            acc[4] = fmaf(f2.x, w, acc[4]); acc[5] = fmaf(f2.y, w, acc[5]);
            acc[6] = fmaf(f3.x, w, acc[6]); acc[7] = fmaf(f3.y, w, acc[7]);
        }
    }
#pragma unroll
    for (int j = 0; j < 8; ++j) {
        acc[j] += __shfl_xor(acc[j], 16);
        acc[j] += __shfl_xor(acc[j], 32);
    }
    const int wave = t >> 6, lane = t & 63;
    if (lane < 16) {
#pragma unroll
        for (int j = 0; j < 8; ++j) red[wave][lane][j] = acc[j];
    }
    __syncthreads();
    if (t < 128) {
        int cc8 = t >> 3, j = t & 7;
        float s = red[0][cc8][j] + red[1][cc8][j] + red[2][cc8][j] + red[3][cc8][j];
        unsafeAtomicAdd(&v[cc8 * 8 + j], s);
    }
}

// ---------------- out = (v @ W3)/N + b3 ----------------
__global__ __launch_bounds__(128) void matvec(const float* __restrict__ v,
                                              const float* __restrict__ W,
                                              const float* __restrict__ b,
                                              float* __restrict__ out, float invN) {
    int c = threadIdx.x;
    float s = 0.f;
    for (int k = 0; k < C; ++k) s = fmaf(v[k], W[(size_t)k * C + c], s);
    out[c] = s * invN + b[c];
}

extern "C" void kernel_launch(void* const* d_in, const int* in_sizes, int n_in,
                              void* d_out, int out_size, void* d_ws, size_t ws_size,
                              hipStream_t stream) {
    const float* x  = (const float*)d_in[0];
    const int*   ei = (const int*)d_in[1];
    const float* W1 = (const float*)d_in[2];
    const float* b1 = (const float*)d_in[3];
    const float* W2 = (const float*)d_in[4];
    const float* b2 = (const float*)d_in[5];
    const float* W3 = (const float*)d_in[6];
    const float* b3 = (const float*)d_in[7];
    float* out = (float*)d_out;

    const int N = in_sizes[0] / C;      // 50000 (< 65536)
    const int E = in_sizes[1] / 2;      // 800000

    char* ws = (char*)d_ws;
    size_t off = 0;
    auto alloc = [&](size_t bytes) { char* p = ws + off; off += (bytes + 255) & ~(size_t)255; return p; };
    ushort* ubuf   = (ushort*)alloc((size_t)N * C * sizeof(ushort));  // u fp16
    ushort* hbuf   = (ushort*)alloc((size_t)N * C * sizeof(ushort));  // h fp16
    unsigned int* interD = (unsigned int*)alloc((size_t)NBINS * CAP * sizeof(unsigned int));
    unsigned int* interS = (unsigned int*)alloc((size_t)NBINS * CAP * sizeof(unsigned int));
    ushort* csr    = (ushort*)alloc(((size_t)NBINS * CAP + 128) * sizeof(ushort));
    int*    rowbeg = (int*)alloc((size_t)N * sizeof(int));
    int*    rowcnt = (int*)alloc((size_t)N * sizeof(int));
    float*  dinv   = (float*)alloc((size_t)N * sizeof(float));
    // zero-init block: ccntD | ccntS | vsum contiguous -> single memset
    char*   zblk   = alloc(2 * NBINS * sizeof(int) + C * sizeof(float));
    int*    ccntD  = (int*)zblk;
    int*    ccntS  = (int*)(zblk + NBINS * sizeof(int));
    float*  vsum   = (float*)(zblk + 2 * NBINS * sizeof(int));
    __half* Wt1    = (__half*)alloc((size_t)C * C * sizeof(__half));
    __half* Wt2    = (__half*)alloc((size_t)C * C * sizeof(__half));

    hipMemsetAsync(zblk, 0, 2 * NBINS * sizeof(int) + C * sizeof(float), stream);

    const int nbuck = (N + LOWM) >> 6;          // 782
    const int nbB = (E + EPB - 1) / EPB;        // 391

    wprep<<<dim3(128, 2), 128, 0, stream>>>(W1, W2, Wt1, Wt2);
    coarse_scatter<<<nbB, 1024, 0, stream>>>(ei, E, ccntD, ccntS, interD, interS);
    bucket_build<<<nbuck, 256, 0, stream>>>(interD, ccntD, N, csr, rowbeg, rowcnt, dinv);

    const int gb = (N + 63) / 64;
    const int nwave = (N + 1) / 2;
    const int ab = (int)(((long long)nwave * 64 + 255) / 256);

    // layer 1
    gemm_mfma<true><<<gb, 256, 0, stream>>>(x, Wt1, dinv, ubuf, N);
    agg_kernel<<<ab, 256, 0, stream>>>(rowbeg, rowcnt, csr, (const uint4*)ubuf, dinv, b1, (uint4*)hbuf, N);
    // layer 2
    gemm_mfma<false><<<gb, 256, 0, stream>>>(hbuf, Wt2, dinv, ubuf, N);
    agg_kernel<<<ab, 256, 0, stream>>>(rowbeg, rowcnt, csr, (const uint4*)ubuf, dinv, b2, (uint4*)hbuf, N);
    // layer 3 collapsed: wreduce computes srcw inline (1 bucket/block, vectorized)
    wreduce<<<nbuck, 256, 0, stream>>>((const __half*)hbuf, dinv, interS, ccntS, vsum, N);
    matvec<<<1, 128, 0, stream>>>(vsum, W3, b3, out, 1.0f / (float)N);
}

// Round 22
// 161.328 us; speedup vs baseline: 1.0402x; 1.0402x over previous
//
#include <hip/hip_runtime.h>
#include <hip/hip_bf16.h>
#include <hip/hip_fp16.h>

// GCN 3-layer embedder. Single-pass dual counting-sort into FIXED-CAPACITY
// coarse buckets (node>>6, CAP=1280; mean 1024, +8 sigma).
// GEMM epilogue scales rows by dinv: u = dinv.*(A@W) stored fp16, so
//   Agg(t)[i] = dinv_i * ( sum_{e: dst=i} u[src_e] + u[i] )
// Layer 3 + mean collapsed:
//   out = ((sum_i w_i * h2[i]) @ W3)/N + b3,  w_i = dinv_i^2 + dinv_i * srcw_i
// wreduce: 1 block per src-bucket, inline srcw, vectorized (R19: 45->~5us).
// scatter: EPB 4096 bracketed optimal (2048 regressed +5.5us: write-amp-bound,
// not occupancy-bound; 8192 was neutral-to-worse in R14).
// agg: 2 nodes/wave, batch-8 row-gathers bracketed optimal (batch-16 cost
// VGPR 68/occupancy; batch-4 was latency-starved).
// NT stores measured -54 us (scattered NT writes lose L2 write-combining): don't.
// srcw/dinv cross-node deps only safe across kernel boundaries (R17 raced).

#define C 128
#define EPB 4096        // edges per block in the scatter kernel (1024 thr x 4)
#define NBINS 1024      // coarse bins (node>>6); 782 used
#define LOWM 63
#define CAP 1280        // bucket capacity (mean 1024, sigma 32)

typedef __attribute__((ext_vector_type(8))) _Float16 half8;
typedef __attribute__((ext_vector_type(4))) float float4v;

__device__ inline void addrow(float4& a0, float4& a1, uint4 uv) {
    float2 f0 = __half22float2(*(__half2*)&uv.x);
    float2 f1 = __half22float2(*(__half2*)&uv.y);
    float2 f2 = __half22float2(*(__half2*)&uv.z);
    float2 f3 = __half22float2(*(__half2*)&uv.w);
    a0.x += f0.x; a0.y += f0.y; a0.z += f1.x; a0.w += f1.y;
    a1.x += f2.x; a1.y += f2.y; a1.z += f3.x; a1.w += f3.y;
}

// ---------------- B1: single-pass dual scatter into fixed-cap buckets ----------------
__global__ __launch_bounds__(1024) void coarse_scatter(const int* __restrict__ ei, int E,
                                                       int* __restrict__ ccntD,
                                                       int* __restrict__ ccntS,
                                                       unsigned int* __restrict__ interD,
                                                       unsigned int* __restrict__ interS) {
    __shared__ int histD[2][NBINS];
    __shared__ int histS[2][NBINS];
    __shared__ int baseD[NBINS], curD[NBINS], baseS[NBINS], curS[NBINS];
    const int t = threadIdx.x, grp = t >> 9;
    histD[0][t] = 0; histD[1][t] = 0; histS[0][t] = 0; histS[1][t] = 0;
    curD[t] = 0; curS[t] = 0;
    __syncthreads();
    int blk = blockIdx.x * EPB;
    int dst[4], src[4];
#pragma unroll
    for (int i = 0; i < 4; ++i) {
        int e = blk + t + i * 1024;
        dst[i] = -1;
        if (e < E) {
            dst[i] = ei[E + e];
            src[i] = ei[e];
            atomicAdd(&histD[grp][dst[i] >> 6], 1);
            atomicAdd(&histS[grp][src[i] >> 6], 1);
        }
    }
    __syncthreads();
    {
        int hD = histD[0][t] + histD[1][t];
        if (hD) baseD[t] = t * CAP + atomicAdd(&ccntD[t], hD);
        int hS = histS[0][t] + histS[1][t];
        if (hS) baseS[t] = t * CAP + atomicAdd(&ccntS[t], hS);
    }
    __syncthreads();
#pragma unroll
    for (int i = 0; i < 4; ++i) {
        if (dst[i] >= 0) {
            int binD = dst[i] >> 6;
            int rD = atomicAdd(&curD[binD], 1);
            interD[baseD[binD] + rD] = ((unsigned int)src[i] << 6) | (unsigned int)(dst[i] & LOWM);
            int binS = src[i] >> 6;
            int rS = atomicAdd(&curS[binS], 1);
            interS[baseS[binS] + rS] = ((unsigned int)dst[i] << 6) | (unsigned int)(src[i] & LOWM);
        }
    }
}

// ---------------- B2: per-dst-bucket finalize: rowbeg, rowcnt, dinv, csr ----------------
__global__ __launch_bounds__(256) void bucket_build(const unsigned int* __restrict__ inter,
                                                    const int* __restrict__ ccntD,
                                                    int N, ushort* __restrict__ csr,
                                                    int* __restrict__ rowbeg,
                                                    int* __restrict__ rowcnt,
                                                    float* __restrict__ dinv) {
    __shared__ int hist[4][64];
    __shared__ int excl[64], cur[64], sc[64];
    const int b = blockIdx.x, t = threadIdx.x, grp = t >> 6;
    const int lo = b * CAP, n = ccntD[b];

    if (t < 64) { hist[0][t] = 0; hist[1][t] = 0; hist[2][t] = 0; hist[3][t] = 0; cur[t] = 0; }
    __syncthreads();
    for (int i = t; i < n; i += 256) atomicAdd(&hist[grp][inter[lo + i] & LOWM], 1);
    __syncthreads();
    int v = 0;
    if (t < 64) { v = hist[0][t] + hist[1][t] + hist[2][t] + hist[3][t]; sc[t] = v; }
    __syncthreads();
    for (int o = 1; o < 64; o <<= 1) {
        int x = 0;
        if (t < 64 && t >= o) x = sc[t - o];
        __syncthreads();
        if (t < 64) sc[t] += x;
        __syncthreads();
    }
    if (t < 64) {
        int ex = sc[t] - v;
        excl[t] = ex;
        int node = b * 64 + t;
        if (node < N) {
            rowbeg[node] = lo + ex;
            rowcnt[node] = v;
            dinv[node] = rsqrtf((float)v + 1.0f);
        }
    }
    __syncthreads();
    for (int i = t; i < n; i += 256) {
        unsigned int pv = inter[lo + i];
        int r = atomicAdd(&cur[pv & LOWM], 1);
        csr[lo + excl[pv & LOWM] + r] = (ushort)(pv >> 6);
    }
}

// ---------------- weight prep: Wt[c][k] = (fp16) W[k][c], for W1,W2 ----------------
__global__ __launch_bounds__(128) void wprep(const float* __restrict__ W1,
                                             const float* __restrict__ W2,
                                             __half* __restrict__ Wt1,
                                             __half* __restrict__ Wt2) {
    const float* W = blockIdx.y ? W2 : W1;
    __half* Wt = blockIdx.y ? Wt2 : Wt1;
    int c = blockIdx.x, k = threadIdx.x;
    Wt[c * 128 + k] = __float2half(W[k * 128 + c]);
}

// ---------------- MFMA GEMM: U[M x 128] = dinv .* (A[M x 128] @ W), fp16 out ----------------
template<bool AF32>
__global__ __launch_bounds__(256) void gemm_mfma(const void* __restrict__ Aptr,
                                                 const __half* __restrict__ Wt,
                                                 const float* __restrict__ dinv,
                                                 ushort* __restrict__ U, int M) {
    __shared__ _Float16 Wsh[128 * 128];   // 32 KB, XOR-swizzled
    const int t = threadIdx.x;

    const float4* Wg4 = (const float4*)Wt;
    float4* Ws4 = (float4*)Wsh;
#pragma unroll
    for (int i = 0; i < 8; ++i) {
        int idx = t + i * 256;
        int row = idx >> 4;
        Ws4[(idx & ~15) | ((idx ^ row) & 7) | (idx & 8)] = Wg4[idx];
    }

    const int wave = t >> 6, lane = t & 63;
    const int row0 = blockIdx.x * 64 + wave * 16;
    const int lr = lane & 15;
    const int lk = lane >> 4;

    half8 afrag[4];
    {
        int gr = row0 + lr; if (gr >= M) gr = M - 1;
        if (AF32) {
            const float* A = (const float*)Aptr;
            const float* ap = A + (size_t)gr * 128 + lk * 8;
#pragma unroll
            for (int ks = 0; ks < 4; ++ks) {
                float4 v0 = *(const float4*)(ap + ks * 32);
                float4 v1 = *(const float4*)(ap + ks * 32 + 4);
                half8 a;
                a[0] = (_Float16)v0.x; a[1] = (_Float16)v0.y; a[2] = (_Float16)v0.z; a[3] = (_Float16)v0.w;
                a[4] = (_Float16)v1.x; a[5] = (_Float16)v1.y; a[6] = (_Float16)v1.z; a[7] = (_Float16)v1.w;
                afrag[ks] = a;
            }
        } else {
            const _Float16* A = (const _Float16*)Aptr;
            const _Float16* ap = A + (size_t)gr * 128 + lk * 8;
#pragma unroll
            for (int ks = 0; ks < 4; ++ks) afrag[ks] = *(const half8*)(ap + ks * 32);
        }
    }

    __syncthreads();

    float4v acc[8];
#pragma unroll
    for (int n = 0; n < 8; ++n) acc[n] = (float4v)0.f;

#pragma unroll
    for (int n = 0; n < 8; ++n) {
        int brow = n * 16 + lr;
#pragma unroll
        for (int ks = 0; ks < 4; ++ks) {
            int f4 = ks * 4 + lk;
            int swz = (f4 & 8) | ((f4 ^ brow) & 7);
            half8 bfr = *(const half8*)(Wsh + (size_t)brow * 128 + swz * 8);
            acc[n] = __builtin_amdgcn_mfma_f32_16x16x32_f16(afrag[ks], bfr, acc[n], 0, 0, 0);
        }
    }

    float dv[4];
#pragma unroll
    for (int r = 0; r < 4; ++r) {
        int gr = row0 + lk * 4 + r;
        dv[r] = (gr < M) ? dinv[gr] : 0.f;
    }
#pragma unroll
    for (int n = 0; n < 8; ++n) {
#pragma unroll
        for (int r = 0; r < 4; ++r) {
            int gr = row0 + lk * 4 + r;
            if (gr < M) {
                __half hv = __float2half(acc[n][r] * dv[r]);
                U[(size_t)gr * 128 + n * 16 + lr] = *(const ushort*)&hv;
            }
        }
    }
}

// ---------------- CSR aggregate: 2 nodes/wave, 8 batched gathers in flight ----------------
__global__ __launch_bounds__(256) void agg_kernel(const int* __restrict__ rowbeg,
                                                  const int* __restrict__ rowcnt,
                                                  const ushort* __restrict__ csr,
                                                  const uint4* __restrict__ u,   // row = 16 uint4
                                                  const float* __restrict__ dinv,
                                                  const float* __restrict__ b,
                                                  uint4* __restrict__ h, int N) {
    int wid = (blockIdx.x * 256 + threadIdx.x) >> 6;
    int n0 = wid * 2;
    if (n0 >= N) return;
    int n1 = n0 + 1;
    bool has1 = n1 < N;
    int lane = threadIdx.x & 63;
    int c8 = lane & 15;          // uint4 index within row
    int g = lane >> 4;           // group 0..3

    int beg0 = rowbeg[n0], end0 = beg0 + rowcnt[n0];
    int beg1 = has1 ? rowbeg[n1] : 0;
    int end1 = has1 ? beg1 + rowcnt[n1] : 0;

    float4 A0 = make_float4(0.f,0.f,0.f,0.f), A1 = A0, B0 = A0, B1 = A0;
    if (g == 0) {                // self-loop terms
        addrow(A0, A1, u[(size_t)n0 * 16 + c8]);
        if (has1) addrow(B0, B1, u[(size_t)n1 * 16 + c8]);
    }

    int k0 = beg0, k1 = beg1;
    while (k0 < end0 || k1 < end1) {
        int cn0 = end0 - k0; cn0 = cn0 < 0 ? 0 : (cn0 > 16 ? 16 : cn0);
        int cn1 = end1 - k1; cn1 = cn1 < 0 ? 0 : (cn1 > 16 ? 16 : cn1);
        int s0 = (lane < cn0) ? (int)csr[k0 + lane] : 0;
        int s1 = (lane < cn1) ? (int)csr[k1 + lane] : 0;
        uint4 r0[4], r1[4];
#pragma unroll
        for (int j = 0; j < 4; ++j) {                      // issue all 8 loads first
            int sj0 = __shfl(s0, g + j * 4);
            int sj1 = __shfl(s1, g + j * 4);
            r0[j] = u[(size_t)sj0 * 16 + c8];
            r1[j] = u[(size_t)sj1 * 16 + c8];
        }
#pragma unroll
        for (int j = 0; j < 4; ++j) {                      // then consume
            int e = g + j * 4;
            if (e < cn0) addrow(A0, A1, r0[j]);
            if (e < cn1) addrow(B0, B1, r1[j]);
        }
        k0 += 16; k1 += 16;
    }

    // combine 4 groups
#pragma unroll
    for (int m = 16; m <= 32; m <<= 1) {
        A0.x += __shfl_xor(A0.x, m); A0.y += __shfl_xor(A0.y, m);
        A0.z += __shfl_xor(A0.z, m); A0.w += __shfl_xor(A0.w, m);
        A1.x += __shfl_xor(A1.x, m); A1.y += __shfl_xor(A1.y, m);
        A1.z += __shfl_xor(A1.z, m); A1.w += __shfl_xor(A1.w, m);
        B0.x += __shfl_xor(B0.x, m); B0.y += __shfl_xor(B0.y, m);
        B0.z += __shfl_xor(B0.z, m); B0.w += __shfl_xor(B0.w, m);
        B1.x += __shfl_xor(B1.x, m); B1.y += __shfl_xor(B1.y, m);
        B1.z += __shfl_xor(B1.z, m); B1.w += __shfl_xor(B1.w, m);
    }

    if (g == 0) {
        float4 bv0 = ((const float4*)b)[c8 * 2];
        float4 bv1 = ((const float4*)b)[c8 * 2 + 1];
        {
            float di = dinv[n0];
            float4 r0v, r1v;
            r0v.x = fmaxf(fmaf(A0.x, di, bv0.x), 0.f);
            r0v.y = fmaxf(fmaf(A0.y, di, bv0.y), 0.f);
            r0v.z = fmaxf(fmaf(A0.z, di, bv0.z), 0.f);
            r0v.w = fmaxf(fmaf(A0.w, di, bv0.w), 0.f);
            r1v.x = fmaxf(fmaf(A1.x, di, bv1.x), 0.f);
            r1v.y = fmaxf(fmaf(A1.y, di, bv1.y), 0.f);
            r1v.z = fmaxf(fmaf(A1.z, di, bv1.z), 0.f);
            r1v.w = fmaxf(fmaf(A1.w, di, bv1.w), 0.f);
            __half2 p0 = __floats2half2_rn(r0v.x, r0v.y);
            __half2 p1 = __floats2half2_rn(r0v.z, r0v.w);
            __half2 p2 = __floats2half2_rn(r1v.x, r1v.y);
            __half2 p3 = __floats2half2_rn(r1v.z, r1v.w);
            uint4 o;
            o.x = *(const unsigned int*)&p0;
            o.y = *(const unsigned int*)&p1;
            o.z = *(const unsigned int*)&p2;
            o.w = *(const unsigned int*)&p3;
            h[(size_t)n0 * 16 + c8] = o;
        }
        if (has1) {
            float di = dinv[n1];
            float4 r0v, r1v;
            r0v.x = fmaxf(fmaf(B0.x, di, bv0.x), 0.f);
            r0v.y = fmaxf(fmaf(B0.y, di, bv0.y), 0.f);
            r0v.z = fmaxf(fmaf(B0.z, di, bv0.z), 0.f);
            r0v.w = fmaxf(fmaf(B0.w, di, bv0.w), 0.f);
            r1v.x = fmaxf(fmaf(B1.x, di, bv1.x), 0.f);
            r1v.y = fmaxf(fmaf(B1.y, di, bv1.y), 0.f);
            r1v.z = fmaxf(fmaf(B1.z, di, bv1.z), 0.f);
            r1v.w = fmaxf(fmaf(B1.w, di, bv1.w), 0.f);
            __half2 p0 = __floats2half2_rn(r0v.x, r0v.y);
            __half2 p1 = __floats2half2_rn(r0v.z, r0v.w);
            __half2 p2 = __floats2half2_rn(r1v.x, r1v.y);
            __half2 p3 = __floats2half2_rn(r1v.z, r1v.w);
            uint4 o;
            o.x = *(const unsigned int*)&p0;
            o.y = *(const unsigned int*)&p1;
            o.z = *(const unsigned int*)&p2;
            o.w = *(const unsigned int*)&p3;
            h[(size_t)n1 * 16 + c8] = o;
        }
    }
}

// ---------------- wreduce: 1 block per src-bucket (64 nodes), vectorized ----------------
__global__ __launch_bounds__(256) void wreduce(const __half* __restrict__ h,
                                               const float* __restrict__ dinv,
                                               const unsigned int* __restrict__ interS,
                                               const int* __restrict__ ccntS,
                                               float* __restrict__ v, int N) {
    __shared__ float facc[64];
    __shared__ float wsh[64];
    __shared__ float red[4][16][8];
    const int b = blockIdx.x, t = threadIdx.x;
    if (t < 64) facc[t] = 0.f;
    __syncthreads();
    {
        int lo = b * CAP, hi = lo + ccntS[b];
        for (int i = lo + t; i < hi; i += 256) {
            unsigned int pv = interS[i];
            atomicAdd(&facc[pv & LOWM], dinv[pv >> 6]);
        }
    }
    __syncthreads();
    if (t < 64) {
        int node = b * 64 + t;
        float w = 0.f;
        if (node < N) { float di = dinv[node]; w = di * (di + facc[t]); }
        wsh[t] = w;
    }
    __syncthreads();

    const int nl = t >> 4;       // node lane 0..15
    const int c8 = t & 15;       // uint4 column
    const uint4* h4 = (const uint4*)h;
    float acc[8];
#pragma unroll
    for (int j = 0; j < 8; ++j) acc[j] = 0.f;
#pragma unroll
    for (int i = 0; i < 4; ++i) {
        int idx = nl + i * 16;
        int node = b * 64 + idx;
        if (node < N) {
            float w = wsh[idx];
            uint4 uv = h4[(size_t)node * 16 + c8];
            float2 f0 = __half22float2(*(__half2*)&uv.x);
            float2 f1 = __half22float2(*(__half2*)&uv.y);
            float2 f2 = __half22float2(*(__half2*)&uv.z);
            float2 f3 = __half22float2(*(__half2*)&uv.w);
            acc[0] = fmaf(f0.x, w, acc[0]); acc[1] = fmaf(f0.y, w, acc[1]);
            acc[2] = fmaf(f1.x, w, acc[2]); acc[3] = fmaf(f1.y, w, acc[3]);
            acc[4] = fmaf(f2.x, w, acc[4]); acc[5] = fmaf(f2.y, w, acc[5]);
            acc[6] = fmaf(f3.x, w, acc[6]); acc[7] = fmaf(f3.y, w, acc[7]);
        }
    }
#pragma unroll
    for (int j = 0; j < 8; ++j) {
        acc[j] += __shfl_xor(acc[j], 16);
        acc[j] += __shfl_xor(acc[j], 32);
    }
    const int wave = t >> 6, lane = t & 63;
    if (lane < 16) {
#pragma unroll
        for (int j = 0; j < 8; ++j) red[wave][lane][j] = acc[j];
    }
    __syncthreads();
    if (t < 128) {
        int cc8 = t >> 3, j = t & 7;
        float s = red[0][cc8][j] + red[1][cc8][j] + red[2][cc8][j] + red[3][cc8][j];
        unsafeAtomicAdd(&v[cc8 * 8 + j], s);
    }
}

// ---------------- out = (v @ W3)/N + b3 ----------------
__global__ __launch_bounds__(128) void matvec(const float* __restrict__ v,
                                              const float* __restrict__ W,
                                              const float* __restrict__ b,
                                              float* __restrict__ out, float invN) {
    int c = threadIdx.x;
    float s = 0.f;
    for (int k = 0; k < C; ++k) s = fmaf(v[k], W[(size_t)k * C + c], s);
    out[c] = s * invN + b[c];
}

extern "C" void kernel_launch(void* const* d_in, const int* in_sizes, int n_in,
                              void* d_out, int out_size, void* d_ws, size_t ws_size,
                              hipStream_t stream) {
    const float* x  = (const float*)d_in[0];
    const int*   ei = (const int*)d_in[1];
    const float* W1 = (const float*)d_in[2];
    const float* b1 = (const float*)d_in[3];
    const float* W2 = (const float*)d_in[4];
    const float* b2 = (const float*)d_in[5];
    const float* W3 = (const float*)d_in[6];
    const float* b3 = (const float*)d_in[7];
    float* out = (float*)d_out;

    const int N = in_sizes[0] / C;      // 50000 (< 65536)
    const int E = in_sizes[1] / 2;      // 800000

    char* ws = (char*)d_ws;
    size_t off = 0;
    auto alloc = [&](size_t bytes) { char* p = ws + off; off += (bytes + 255) & ~(size_t)255; return p; };
    ushort* ubuf   = (ushort*)alloc((size_t)N * C * sizeof(ushort));  // u fp16
    ushort* hbuf   = (ushort*)alloc((size_t)N * C * sizeof(ushort));  // h fp16
    unsigned int* interD = (unsigned int*)alloc((size_t)NBINS * CAP * sizeof(unsigned int));
    unsigned int* interS = (unsigned int*)alloc((size_t)NBINS * CAP * sizeof(unsigned int));
    ushort* csr    = (ushort*)alloc(((size_t)NBINS * CAP + 128) * sizeof(ushort));
    int*    rowbeg = (int*)alloc((size_t)N * sizeof(int));
    int*    rowcnt = (int*)alloc((size_t)N * sizeof(int));
    float*  dinv   = (float*)alloc((size_t)N * sizeof(float));
    // zero-init block: ccntD | ccntS | vsum contiguous -> single memset
    char*   zblk   = alloc(2 * NBINS * sizeof(int) + C * sizeof(float));
    int*    ccntD  = (int*)zblk;
    int*    ccntS  = (int*)(zblk + NBINS * sizeof(int));
    float*  vsum   = (float*)(zblk + 2 * NBINS * sizeof(int));
    __half* Wt1    = (__half*)alloc((size_t)C * C * sizeof(__half));
    __half* Wt2    = (__half*)alloc((size_t)C * C * sizeof(__half));

    hipMemsetAsync(zblk, 0, 2 * NBINS * sizeof(int) + C * sizeof(float), stream);

    const int nbuck = (N + LOWM) >> 6;          // 782
    const int nbB = (E + EPB - 1) / EPB;        // 196

    wprep<<<dim3(128, 2), 128, 0, stream>>>(W1, W2, Wt1, Wt2);
    coarse_scatter<<<nbB, 1024, 0, stream>>>(ei, E, ccntD, ccntS, interD, interS);
    bucket_build<<<nbuck, 256, 0, stream>>>(interD, ccntD, N, csr, rowbeg, rowcnt, dinv);

    const int gb = (N + 63) / 64;
    const int nwave = (N + 1) / 2;
    const int ab = (int)(((long long)nwave * 64 + 255) / 256);

    // layer 1
    gemm_mfma<true><<<gb, 256, 0, stream>>>(x, Wt1, dinv, ubuf, N);
    agg_kernel<<<ab, 256, 0, stream>>>(rowbeg, rowcnt, csr, (const uint4*)ubuf, dinv, b1, (uint4*)hbuf, N);
    // layer 2
    gemm_mfma<false><<<gb, 256, 0, stream>>>(hbuf, Wt2, dinv, ubuf, N);
    agg_kernel<<<ab, 256, 0, stream>>>(rowbeg, rowcnt, csr, (const uint4*)ubuf, dinv, b2, (uint4*)hbuf, N);
    // layer 3 collapsed: wreduce computes srcw inline (1 bucket/block, vectorized)
    wreduce<<<nbuck, 256, 0, stream>>>((const __half*)hbuf, dinv, interS, ccntS, vsum, N);
    matvec<<<1, 128, 0, stream>>>(vsum, W3, b3, out, 1.0f / (float)N);
}